// Round 1
// baseline (374.429 us; speedup 1.0000x reference)
//
#include <hip/hip_runtime.h>
#include <hip/hip_bf16.h>

#define N_ROWS 262144
#define DDIM   256
#define PROTO  512
#define BM     64
#define TILES  4
#define GBLK   1024

typedef __bf16 bf16x8 __attribute__((ext_vector_type(8)));
typedef float  f32x4  __attribute__((ext_vector_type(4)));

__device__ __forceinline__ unsigned short f2bf(float f) {
  unsigned int u = __float_as_uint(f);
  unsigned int r = (u + 0x7FFFu + ((u >> 16) & 1u)) >> 16;  // RNE
  return (unsigned short)r;
}

// ---------------- prep: prototypes fp32 -> bf16, p2 = rowwise |p|^2 ----------------
__global__ void prep_proto(const float* __restrict__ Pm,
                           unsigned short* __restrict__ PB,
                           float* __restrict__ P2) {
  int p = blockIdx.x;     // 512
  int t = threadIdx.x;    // 256
  float v = Pm[p * DDIM + t];
  PB[p * DDIM + t] = f2bf(v);
  float sq = v * v;
  #pragma unroll
  for (int m = 1; m < 64; m <<= 1) sq += __shfl_xor(sq, m);
  __shared__ float ws4[4];
  if ((t & 63) == 0) ws4[t >> 6] = sq;
  __syncthreads();
  if (t == 0) P2[p] = (ws4[0] + ws4[1]) + (ws4[2] + ws4[3]);
}

// ---------------- main: fused GEMM + row/col min ----------------
// grid 1024, block 512 (8 waves). Block b handles rows [b*256, b*256+256) as 4 tiles of 64.
// Wave w handles cols [w*64, w*64+64).
#define A_STRIDE 264   // ushorts per row (528B, breaks 32-way bank conflict -> 2-way)
#define B_STRIDE 40    // ushorts per row (80B)

__global__ __launch_bounds__(512, 4)
void proto_main(const float* __restrict__ Z, const unsigned short* __restrict__ PB,
                const float* __restrict__ P2, float* __restrict__ colpart,
                float* __restrict__ rowpart) {
  __shared__ __align__(16) unsigned short A_lds[BM * A_STRIDE];     // 33792 B
  __shared__ __align__(16) unsigned short B_lds[PROTO * B_STRIDE];  // 40960 B
  __shared__ float p2s[PROTO];
  __shared__ float z2s[BM];
  __shared__ float rowred[BM * 8];

  const int t   = threadIdx.x;
  const int w   = t >> 6;   // wave 0..7
  const int l   = t & 63;
  const int l15 = l & 15;
  const int lg  = l >> 4;   // 0..3

  p2s[t] = P2[t];           // t < 512

  float colmin[4];
  #pragma unroll
  for (int j = 0; j < 4; ++j) colmin[j] = 3.4e38f;
  float rs = 0.0f;          // row-min sqrt accumulator (valid for t < 64)

  for (int tt = 0; tt < TILES; ++tt) {
    const int row0 = (blockIdx.x * TILES + tt) * BM;

    __syncthreads();  // prev tile's LDS reads + rowred consumption done

    // ---- stage A tile (64 x 256) fp32->bf16 + fp32 z2 ----
    {
      const int ar = t >> 3;   // row 0..63 (8 threads per row)
      const int cb = t & 7;
      float zacc = 0.f;
      const float4* Zv = (const float4*)Z + (size_t)(row0 + ar) * (DDIM / 4);
      #pragma unroll
      for (int jj = 0; jj < 4; ++jj) {
        int c = cb + jj * 8;           // 8-float chunk index 0..31
        float4 a0 = Zv[c * 2];
        float4 a1 = Zv[c * 2 + 1];
        zacc += a0.x*a0.x + a0.y*a0.y + a0.z*a0.z + a0.w*a0.w
              + a1.x*a1.x + a1.y*a1.y + a1.z*a1.z + a1.w*a1.w;
        uint4 pk;
        pk.x = (unsigned)f2bf(a0.x) | ((unsigned)f2bf(a0.y) << 16);
        pk.y = (unsigned)f2bf(a0.z) | ((unsigned)f2bf(a0.w) << 16);
        pk.z = (unsigned)f2bf(a1.x) | ((unsigned)f2bf(a1.y) << 16);
        pk.w = (unsigned)f2bf(a1.z) | ((unsigned)f2bf(a1.w) << 16);
        *(uint4*)&A_lds[ar * A_STRIDE + c * 8] = pk;
      }
      zacc += __shfl_xor(zacc, 1);
      zacc += __shfl_xor(zacc, 2);
      zacc += __shfl_xor(zacc, 4);
      if (cb == 0) z2s[ar] = zacc;
    }

    f32x4 acc[4][4];
    #pragma unroll
    for (int i = 0; i < 4; ++i)
      #pragma unroll
      for (int j = 0; j < 4; ++j)
        acc[i][j] = (f32x4){0.f, 0.f, 0.f, 0.f};

    // ---- K loop: 8 steps of BK=32 ----
    for (int ks = 0; ks < 8; ++ks) {
      __syncthreads();  // prev B reads done (also makes A visible at ks=0)
      {
        const uint4* PBv = (const uint4*)PB;
        #pragma unroll
        for (int jj = 0; jj < 4; ++jj) {
          int c = jj * 512 + t;
          int prow = c >> 2;
          int ko   = c & 3;
          uint4 v = PBv[prow * (DDIM / 8) + ks * 4 + ko];
          *(uint4*)&B_lds[prow * B_STRIDE + ko * 8] = v;
        }
      }
      __syncthreads();

      bf16x8 af[4], bg[4];
      #pragma unroll
      for (int i = 0; i < 4; ++i) {
        int arow = i * 16 + l15;
        af[i] = *(const bf16x8*)&A_lds[arow * A_STRIDE + ks * 32 + lg * 8];
      }
      #pragma unroll
      for (int j = 0; j < 4; ++j) {
        int prow = (w * 4 + j) * 16 + l15;
        bg[j] = *(const bf16x8*)&B_lds[prow * B_STRIDE + lg * 8];
      }
      #pragma unroll
      for (int i = 0; i < 4; ++i)
        #pragma unroll
        for (int j = 0; j < 4; ++j)
          acc[i][j] = __builtin_amdgcn_mfma_f32_16x16x32_bf16(af[i], bg[j], acc[i][j], 0, 0, 0);
    }

    // ---- epilogue: sq = z2 + p2 - 2*dot (clamped), row/col mins ----
    float cmin[4];
    #pragma unroll
    for (int j = 0; j < 4; ++j) cmin[j] = 3.4e38f;

    #pragma unroll
    for (int i = 0; i < 4; ++i) {
      #pragma unroll
      for (int r = 0; r < 4; ++r) {
        int arow = i * 16 + lg * 4 + r;     // C layout: col=lane&15, row=(lane>>4)*4+r
        float z2 = z2s[arow];
        float m = 3.4e38f;
        #pragma unroll
        for (int j = 0; j < 4; ++j) {
          int col = (w * 4 + j) * 16 + l15;
          float sq = z2 + p2s[col] - 2.0f * acc[i][j][r];
          sq = fmaxf(sq, 0.0f);
          m = fminf(m, sq);
          cmin[j] = fminf(cmin[j], sq);
        }
        // min across the 16 cols held by l&15 lanes (same lg group)
        m = fminf(m, __shfl_xor(m, 1));
        m = fminf(m, __shfl_xor(m, 2));
        m = fminf(m, __shfl_xor(m, 4));
        m = fminf(m, __shfl_xor(m, 8));
        if (l15 == 0) rowred[arow * 8 + w] = m;
      }
    }
    // col-min across the 4 row-groups (lg)
    #pragma unroll
    for (int j = 0; j < 4; ++j) {
      float c = cmin[j];
      c = fminf(c, __shfl_xor(c, 16));
      c = fminf(c, __shfl_xor(c, 32));
      colmin[j] = fminf(colmin[j], c);
    }
    __syncthreads();
    if (t < 64) {
      float m = rowred[t * 8];
      #pragma unroll
      for (int ww = 1; ww < 8; ++ww) m = fminf(m, rowred[t * 8 + ww]);
      rs += sqrtf(m);
    }
  }

  // ---- block outputs ----
  if (l < 16) {
    #pragma unroll
    for (int j = 0; j < 4; ++j)
      colpart[(size_t)blockIdx.x * PROTO + w * 64 + j * 16 + l] = colmin[j];
  }
  if (t < 64) {
    float v = rs;
    v += __shfl_xor(v, 1);  v += __shfl_xor(v, 2);  v += __shfl_xor(v, 4);
    v += __shfl_xor(v, 8);  v += __shfl_xor(v, 16); v += __shfl_xor(v, 32);
    if (t == 0) rowpart[blockIdx.x] = v;
  }
}

// ---------------- col reduce: min over 1024 partials per col, then sqrt ----------------
__global__ void col_reduce(const float* __restrict__ colpart, float* __restrict__ colfin) {
  int c = blockIdx.x;    // 512
  int t = threadIdx.x;   // 256
  float m = 3.4e38f;
  for (int g = t; g < GBLK; g += 256) m = fminf(m, colpart[(size_t)g * PROTO + c]);
  #pragma unroll
  for (int mm = 1; mm < 64; mm <<= 1) m = fminf(m, __shfl_xor(m, mm));
  __shared__ float ws4[4];
  if ((t & 63) == 0) ws4[t >> 6] = m;
  __syncthreads();
  if (t == 0) colfin[c] = sqrtf(fminf(fminf(ws4[0], ws4[1]), fminf(ws4[2], ws4[3])));
}

// ---------------- final combine ----------------
__global__ void final_reduce(const float* __restrict__ colfin,
                             const float* __restrict__ rowpart,
                             float* __restrict__ out) {
  int t = threadIdx.x;   // 512
  float sc = colfin[t];
  float sr = rowpart[t] + rowpart[t + 512];
  #pragma unroll
  for (int mm = 1; mm < 64; mm <<= 1) { sc += __shfl_xor(sc, mm); sr += __shfl_xor(sr, mm); }
  __shared__ float wc[8], wr[8];
  if ((t & 63) == 0) { wc[t >> 6] = sc; wr[t >> 6] = sr; }
  __syncthreads();
  if (t == 0) {
    float tc = 0.f, tr = 0.f;
    #pragma unroll
    for (int i = 0; i < 8; ++i) { tc += wc[i]; tr += wr[i]; }
    out[0] = 0.05f * (tr / (float)N_ROWS) + 0.05f * (tc / (float)PROTO);
  }
}

extern "C" void kernel_launch(void* const* d_in, const int* in_sizes, int n_in,
                              void* d_out, int out_size, void* d_ws, size_t ws_size,
                              hipStream_t stream) {
  const float* z  = (const float*)d_in[0];
  const float* pv = (const float*)d_in[1];
  char* ws = (char*)d_ws;
  unsigned short* PB = (unsigned short*)ws;                               // 524288 B
  float* P2      = (float*)(ws + 524288);                                 // 2048 B
  float* colpart = (float*)(ws + 524288 + 2048);                          // 1024*512*4 = 2097152 B
  float* rowpart = (float*)(ws + 524288 + 2048 + 2097152);                // 4096 B
  float* colfin  = (float*)(ws + 524288 + 2048 + 2097152 + 4096);         // 2048 B

  prep_proto<<<PROTO, DDIM, 0, stream>>>(pv, PB, P2);
  proto_main<<<GBLK, 512, 0, stream>>>(z, PB, P2, colpart, rowpart);
  col_reduce<<<PROTO, 256, 0, stream>>>(colpart, colfin);
  final_reduce<<<1, 512, 0, stream>>>(colfin, rowpart, (float*)d_out);
}

// Round 2
// 285.934 us; speedup vs baseline: 1.3095x; 1.3095x over previous
//
#include <hip/hip_runtime.h>
#include <hip/hip_bf16.h>

#define N_ROWS 262144
#define DDIM   256
#define PROTO  512
#define BM     64
#define TILES  4
#define GBLK   1024
#define A_STRIDE 264   // ushorts per row (528B = 33*16B; 2-way bank alias only -> free)

typedef __bf16 bf16x8 __attribute__((ext_vector_type(8)));
typedef __bf16 bf16x4 __attribute__((ext_vector_type(4)));
typedef float  f32x4  __attribute__((ext_vector_type(4)));

// ---------------- prep: prototypes fp32 -> bf16 in MFMA-fragment order, p2 ----------------
// PBf layout: frag2 = p>>4 (32 groups of 16 protos), ks = k>>5, lane l = ((k>>3)&3)*16 + (p&15),
// elem e = k&7.  idx = frag2*4096 + ks*512 + l*8 + e.  A wave's bg[j][ks] load is then a
// fully coalesced 16B/lane read.
__global__ void prep_proto(const float* __restrict__ Pm,
                           unsigned short* __restrict__ PBf,
                           float* __restrict__ P2) {
  int p = blockIdx.x;     // 512
  int k = threadIdx.x;    // 256
  float v = Pm[p * DDIM + k];
  int idx = (p >> 4) * 4096 + (k >> 5) * 512 + ((((k >> 3) & 3) * 16) + (p & 15)) * 8 + (k & 7);
  ((__bf16*)PBf)[idx] = (__bf16)v;
  float sq = v * v;
  #pragma unroll
  for (int m = 1; m < 64; m <<= 1) sq += __shfl_xor(sq, m);
  __shared__ float ws4[4];
  if ((k & 63) == 0) ws4[k >> 6] = sq;
  __syncthreads();
  if (k == 0) P2[p] = (ws4[0] + ws4[1]) + (ws4[2] + ws4[3]);
}

// ---------------- main: fused GEMM + row/col min ----------------
// grid 1024 x block 1024 (16 waves). Block b: rows [b*256, b*256+256) as 4 tiles of 64.
// Wave w owns proto cols [w*32, w*32+32), held entirely in registers (bg[2][8]).
// K-loop has NO barriers and NO B memory traffic.
__global__ __launch_bounds__(1024, 4)
void proto_main(const float* __restrict__ Z, const unsigned short* __restrict__ PBf,
                const float* __restrict__ P2, float* __restrict__ colpart,
                float* __restrict__ rowpart) {
  __shared__ __align__(16) unsigned short A_lds[BM * A_STRIDE];  // 33792 B
  __shared__ float z2s[BM];
  __shared__ float rowred[BM * 16];                              // 4096 B

  const int t   = threadIdx.x;
  const int w   = t >> 6;   // wave 0..15
  const int l   = t & 63;
  const int l15 = l & 15;
  const int lg  = l >> 4;   // 0..3

  // ---- B slice into registers (once per block) ----
  bf16x8 bg[2][8];
  #pragma unroll
  for (int j = 0; j < 2; ++j)
    #pragma unroll
    for (int ks = 0; ks < 8; ++ks)
      bg[j][ks] = *(const bf16x8*)&PBf[(size_t)((w * 2 + j) * 8 + ks) * 512 + l * 8];

  float p2r[2];
  p2r[0] = P2[w * 32 + l15];
  p2r[1] = P2[w * 32 + 16 + l15];

  float colmin[2] = {3.4e38f, 3.4e38f};
  float rs = 0.0f;          // row-min sqrt accumulator (valid for t < 64)

  const int sr = t >> 4;    // staging row 0..63 (16 threads per row)
  const int sc = t & 15;

  for (int tt = 0; tt < TILES; ++tt) {
    const int row0 = (blockIdx.x * TILES + tt) * BM;

    __syncthreads();  // B1: prev tile's A_lds reads + rowred reads done

    // ---- stage A tile (64 x 256) fp32->bf16 + fp32 z2 ----
    {
      const float4* Zv = (const float4*)Z + (size_t)(row0 + sr) * (DDIM / 4);
      float zacc = 0.f;
      #pragma unroll
      for (int jj = 0; jj < 4; ++jj) {
        float4 a = Zv[sc + jj * 16];
        zacc += a.x * a.x + a.y * a.y + a.z * a.z + a.w * a.w;
        bf16x4 pk;
        pk[0] = (__bf16)a.x; pk[1] = (__bf16)a.y; pk[2] = (__bf16)a.z; pk[3] = (__bf16)a.w;
        *(bf16x4*)&A_lds[sr * A_STRIDE + (sc + jj * 16) * 4] = pk;
      }
      zacc += __shfl_xor(zacc, 1);
      zacc += __shfl_xor(zacc, 2);
      zacc += __shfl_xor(zacc, 4);
      zacc += __shfl_xor(zacc, 8);
      if (sc == 0) z2s[sr] = zacc;
    }
    __syncthreads();  // B2: A_lds + z2s visible

    f32x4 acc[4][2];
    #pragma unroll
    for (int i = 0; i < 4; ++i)
      #pragma unroll
      for (int j = 0; j < 2; ++j)
        acc[i][j] = (f32x4){0.f, 0.f, 0.f, 0.f};

    // ---- K loop: 8 steps of BK=32, no barriers, B from registers ----
    #pragma unroll
    for (int ks = 0; ks < 8; ++ks) {
      bf16x8 af[4];
      #pragma unroll
      for (int i = 0; i < 4; ++i)
        af[i] = *(const bf16x8*)&A_lds[(i * 16 + l15) * A_STRIDE + ks * 32 + lg * 8];
      #pragma unroll
      for (int i = 0; i < 4; ++i)
        #pragma unroll
        for (int j = 0; j < 2; ++j)
          acc[i][j] = __builtin_amdgcn_mfma_f32_16x16x32_bf16(af[i], bg[j][ks], acc[i][j], 0, 0, 0);
    }

    // ---- epilogue: sq = z2 + p2 - 2*dot (clamped), row/col mins ----
    float cmin[2] = {3.4e38f, 3.4e38f};
    #pragma unroll
    for (int i = 0; i < 4; ++i) {
      #pragma unroll
      for (int r = 0; r < 4; ++r) {
        int arow = i * 16 + lg * 4 + r;     // C layout: col=lane&15, row=(lane>>4)*4+r
        float z2 = z2s[arow];
        float m = 3.4e38f;
        #pragma unroll
        for (int j = 0; j < 2; ++j) {
          float sq = fmaxf(z2 + p2r[j] - 2.0f * acc[i][j][r], 0.0f);
          m = fminf(m, sq);
          cmin[j] = fminf(cmin[j], sq);
        }
        m = fminf(m, __shfl_xor(m, 1));
        m = fminf(m, __shfl_xor(m, 2));
        m = fminf(m, __shfl_xor(m, 4));
        m = fminf(m, __shfl_xor(m, 8));
        if (l15 == 0) rowred[arow * 16 + w] = m;
      }
    }
    #pragma unroll
    for (int j = 0; j < 2; ++j) {
      float c = cmin[j];
      c = fminf(c, __shfl_xor(c, 16));
      c = fminf(c, __shfl_xor(c, 32));
      colmin[j] = fminf(colmin[j], c);
    }
    __syncthreads();  // B3: rowred visible
    if (t < 64) {
      float m = rowred[t * 16];
      #pragma unroll
      for (int ww = 1; ww < 16; ++ww) m = fminf(m, rowred[t * 16 + ww]);
      rs += sqrtf(m);
    }
  }

  // ---- block outputs ----
  if (l < 16) {
    colpart[(size_t)blockIdx.x * PROTO + w * 32 + l]      = colmin[0];
    colpart[(size_t)blockIdx.x * PROTO + w * 32 + 16 + l] = colmin[1];
  }
  if (t < 64) {
    float v = rs;
    v += __shfl_xor(v, 1);  v += __shfl_xor(v, 2);  v += __shfl_xor(v, 4);
    v += __shfl_xor(v, 8);  v += __shfl_xor(v, 16); v += __shfl_xor(v, 32);
    if (t == 0) rowpart[blockIdx.x] = v;
  }
}

// ---------------- col reduce: min over 1024 partials per col, then sqrt ----------------
__global__ void col_reduce(const float* __restrict__ colpart, float* __restrict__ colfin) {
  int c = blockIdx.x;    // 512
  int t = threadIdx.x;   // 256
  float m = 3.4e38f;
  for (int g = t; g < GBLK; g += 256) m = fminf(m, colpart[(size_t)g * PROTO + c]);
  #pragma unroll
  for (int mm = 1; mm < 64; mm <<= 1) m = fminf(m, __shfl_xor(m, mm));
  __shared__ float ws4[4];
  if ((t & 63) == 0) ws4[t >> 6] = m;
  __syncthreads();
  if (t == 0) colfin[c] = sqrtf(fminf(fminf(ws4[0], ws4[1]), fminf(ws4[2], ws4[3])));
}

// ---------------- final combine ----------------
__global__ void final_reduce(const float* __restrict__ colfin,
                             const float* __restrict__ rowpart,
                             float* __restrict__ out) {
  int t = threadIdx.x;   // 512
  float sc = colfin[t];
  float sr = rowpart[t] + rowpart[t + 512];
  #pragma unroll
  for (int mm = 1; mm < 64; mm <<= 1) { sc += __shfl_xor(sc, mm); sr += __shfl_xor(sr, mm); }
  __shared__ float wc[8], wr[8];
  if ((t & 63) == 0) { wc[t >> 6] = sc; wr[t >> 6] = sr; }
  __syncthreads();
  if (t == 0) {
    float tc = 0.f, tr = 0.f;
    #pragma unroll
    for (int i = 0; i < 8; ++i) { tc += wc[i]; tr += wr[i]; }
    out[0] = 0.05f * (tr / (float)N_ROWS) + 0.05f * (tc / (float)PROTO);
  }
}

extern "C" void kernel_launch(void* const* d_in, const int* in_sizes, int n_in,
                              void* d_out, int out_size, void* d_ws, size_t ws_size,
                              hipStream_t stream) {
  const float* z  = (const float*)d_in[0];
  const float* pv = (const float*)d_in[1];
  char* ws = (char*)d_ws;
  unsigned short* PBf = (unsigned short*)ws;                              // 262144 B used
  float* P2      = (float*)(ws + 524288);                                 // 2048 B
  float* colpart = (float*)(ws + 524288 + 2048);                          // 1024*512*4 = 2097152 B
  float* rowpart = (float*)(ws + 524288 + 2048 + 2097152);                // 4096 B
  float* colfin  = (float*)(ws + 524288 + 2048 + 2097152 + 4096);         // 2048 B

  prep_proto<<<PROTO, DDIM, 0, stream>>>(pv, PBf, P2);
  proto_main<<<GBLK, 1024, 0, stream>>>(z, PBf, P2, colpart, rowpart);
  col_reduce<<<PROTO, 256, 0, stream>>>(colpart, colfin);
  final_reduce<<<1, 512, 0, stream>>>(colfin, rowpart, (float*)d_out);
}